// Round 10
// baseline (271.011 us; speedup 1.0000x reference)
//
#include <hip/hip_runtime.h>
#include <stdint.h>

typedef unsigned short u16;
typedef uint32_t u32;
typedef unsigned long long u64;
typedef short bf16x8 __attribute__((ext_vector_type(8)));
typedef float f32x4 __attribute__((ext_vector_type(4)));
typedef float f32x16 __attribute__((ext_vector_type(16)));

#define MFMA16 __builtin_amdgcn_mfma_f32_16x16x32_bf16
#define MFMA32 __builtin_amdgcn_mfma_f32_32x32x16_bf16
#define L2E 1.44269504088896340736f

static __device__ __forceinline__ u16 f2bf(float f) {
  union { float f; u32 u; } v; v.f = f;
  u32 r = v.u + 0x7FFFu + ((v.u >> 16) & 1u);
  return (u16)(r >> 16);
}

// hardware packed f32x2 -> bf16x2 (RNE); no builtin on gfx950 (guide m240)
static __device__ __forceinline__ u32 cvtpk(float lo, float hi) {
  u32 r;
  asm("v_cvt_pk_bf16_f32 %0, %1, %2" : "=v"(r) : "v"(lo), "v"(hi));
  return r;
}

static __device__ __forceinline__ void glds16(const u16* g, u16* l) {
  __builtin_amdgcn_global_load_lds((const __attribute__((address_space(1))) void*)g,
                                   (__attribute__((address_space(3))) void*)l, 16, 0, 0);
}

// -------- transpose-convert the 4 weight matrices: Wt[n][k] = bf16(W[k][n]) --------
__global__ __launch_bounds__(256) void wtrans_kernel(
    const float* __restrict__ w0, const float* __restrict__ w1,
    const float* __restrict__ w2, const float* __restrict__ w3,
    u16* __restrict__ t0, u16* __restrict__ t1, u16* __restrict__ t2, u16* __restrict__ t3) {
  const float* w = (blockIdx.z == 0) ? w0 : (blockIdx.z == 1) ? w1 : (blockIdx.z == 2) ? w2 : w3;
  u16* t = (blockIdx.z == 0) ? t0 : (blockIdx.z == 1) ? t1 : (blockIdx.z == 2) ? t2 : t3;
  __shared__ float tile[64][65];
  const int bx = blockIdx.x, by = blockIdx.y;
#pragma unroll
  for (int i = 0; i < 16; ++i) {
    int idx = i * 256 + threadIdx.x;
    int r = idx >> 6, c = idx & 63;
    tile[r][c] = w[(size_t)(by * 64 + r) * 1024 + bx * 64 + c];
  }
  __syncthreads();
#pragma unroll
  for (int i = 0; i < 16; ++i) {
    int idx = i * 256 + threadIdx.x;
    int r = idx >> 6, c = idx & 63;
    t[(size_t)(bx * 64 + r) * 1024 + by * 64 + c] = f2bf(tile[c][r]);
  }
}

// -------- pack int32 mask (0/1) into bits: word w covers k = 32w..32w+31 --------
__global__ __launch_bounds__(256) void packmask_kernel(const int* __restrict__ m,
                                                       u32* __restrict__ pmo) {
  const size_t i = (size_t)blockIdx.x * 256 + threadIdx.x;
  const int lane = threadIdx.x & 63;
  unsigned long long b = __ballot(m[i] != 0);
  if (lane == 0) pmo[i >> 5] = (u32)b;
  else if (lane == 32) pmo[i >> 5] = (u32)(b >> 32);
}

// -------- bf16 GEMM: BM=256 BN=128 BK=64, 512 thr (8 waves 4Mx2N), 3-buffer --------
// counted-vmcnt pipeline (T4), XOR-swizzled LDS (T2), setprio (T5).
// OM=1: bf16 A staged via global_load_lds (pre-swizzled source) — round-8 path.
// OM=0/2: FP32 A fused-converted (T14): global f32 loads -> TWO register sets
// (tile n lives in set n%2; each set consumed by AWRITE exactly one iteration
// before it is re-issued — the round-9 bug was a single clobbered set) ->
// v_cvt_pk_bf16_f32 -> swizzled ds_write_b128. 10 VMEM/tile (8 A + 2 B-glds);
// end of iter t: vmcnt(10) = tile t+1 landed (t+2 stays in flight), AWRITE(t+1),
// lgkmcnt(0), s_barrier. Compiler's register-dep waitcnt independently guards A.
// Bt: (N,K) bf16 row-major (= B^T).
// OM: 0 = bf16 row-major out, 1 = f32 row-major out, 2 = bf16 V^T (B,H,D,S) out.
template <int OM>
__global__ __launch_bounds__(512, 2) void gemm_kernel(
    const void* __restrict__ Apv, const u16* __restrict__ Bt, const float* __restrict__ bias,
    void* __restrict__ Cout, float oscale) {
  constexpr int K = 1024, N = 1024;
  constexpr int NT = K / 64;  // 16 K-tiles
  constexpr bool AF32 = (OM != 1);
  __shared__ u16 As[3][256 * 64];  // 96 KB
  __shared__ u16 Bs[3][128 * 64];  // 48 KB
  const u16* Ab = (const u16*)Apv;
  const float* Af = (const float*)Apv;
  const int tid = threadIdx.x;
  const int lane = tid & 63;
  const int wid = tid >> 6;       // 0..7
  const int l15 = lane & 15;
  const int lg = lane >> 4;
  const int row0 = blockIdx.x * 256;
  const int col0 = blockIdx.y * 128;
  const int wr = wid >> 1, wc = wid & 1;  // 4M x 2N wave grid
  const int swf = (l15 & 7) << 3;         // read-side XOR swizzle (u16 units)
  const f32x4 fzero = {0.f, 0.f, 0.f, 0.f};

  f32x4 acc[4][4];
#pragma unroll
  for (int m = 0; m < 4; ++m)
#pragma unroll
    for (int n = 0; n < 4; ++n) acc[m][n] = fzero;

  float4 aA[8], aB[8];  // two in-flight A register sets (tile n -> set n%2)

#define BGLDS(buf, k0)                                                         \
  do {                                                                         \
    _Pragma("unroll") for (int i = 0; i < 2; ++i) {                            \
      int e = (i * 512 + tid) * 8;                                             \
      int r = e >> 6, c = e & 63;                                              \
      int cs = c ^ ((r & 7) << 3);                                             \
      glds16(Bt + (size_t)(col0 + r) * K + (k0) + cs, &Bs[buf][e]);            \
    }                                                                          \
  } while (0)

  // bf16-A staging (OM=1): 4 A-glds + 2 B-glds, pre-swizzled source
#define GSTAGE_BF(buf, k0)                                                     \
  do {                                                                         \
    _Pragma("unroll") for (int i = 0; i < 4; ++i) {                            \
      int e = (i * 512 + tid) * 8;                                             \
      int r = e >> 6, c = e & 63;                                              \
      int cs = c ^ ((r & 7) << 3);                                             \
      glds16(Ab + (size_t)(row0 + r) * K + (k0) + cs, &As[buf][e]);            \
    }                                                                          \
    BGLDS(buf, k0);                                                            \
  } while (0)

  // f32-A issue into register set `areg` (linear global read) + B-glds
#define GISSUE(areg, bufB, k0)                                                 \
  do {                                                                         \
    _Pragma("unroll") for (int i = 0; i < 4; ++i) {                            \
      int e = (i * 512 + tid) * 8;                                             \
      int r = e >> 6, c = e & 63;                                              \
      const float* src = Af + (size_t)(row0 + r) * K + (k0) + c;               \
      areg[2 * i] = *(const float4*)src;                                       \
      areg[2 * i + 1] = *(const float4*)(src + 4);                             \
    }                                                                          \
    BGLDS(bufB, k0);                                                           \
  } while (0)

  // convert + swizzled ds_write_b128 of register set `areg` into As[bufw]
#define AWRITE(areg, bufw)                                                     \
  do {                                                                         \
    _Pragma("unroll") for (int i = 0; i < 4; ++i) {                            \
      int e = (i * 512 + tid) * 8;                                             \
      int r = e >> 6, c = e & 63;                                              \
      int cs = c ^ ((r & 7) << 3);                                             \
      uint4 w;                                                                 \
      w.x = cvtpk(areg[2 * i].x, areg[2 * i].y);                               \
      w.y = cvtpk(areg[2 * i].z, areg[2 * i].w);                               \
      w.z = cvtpk(areg[2 * i + 1].x, areg[2 * i + 1].y);                       \
      w.w = cvtpk(areg[2 * i + 1].z, areg[2 * i + 1].w);                       \
      *(uint4*)(&As[bufw][r * 64 + cs]) = w;                                   \
    }                                                                          \
  } while (0)

#define COMPUTE(buf)                                                           \
  do {                                                                         \
    __builtin_amdgcn_s_setprio(1);                                             \
    _Pragma("unroll") for (int ks = 0; ks < 2; ++ks) {                         \
      const int koff = ks * 32 + lg * 8;                                       \
      bf16x8 af[4], bfr[4];                                                    \
      _Pragma("unroll") for (int m = 0; m < 4; ++m)                            \
        af[m] = *(const bf16x8*)(&As[buf][(wr * 64 + m * 16 + l15) * 64 +      \
                                          (koff ^ swf)]);                      \
      _Pragma("unroll") for (int n = 0; n < 4; ++n)                            \
        bfr[n] = *(const bf16x8*)(&Bs[buf][(wc * 64 + n * 16 + l15) * 64 +     \
                                           (koff ^ swf)]);                     \
      _Pragma("unroll") for (int m = 0; m < 4; ++m)                            \
        _Pragma("unroll") for (int n = 0; n < 4; ++n)                          \
          acc[m][n] = MFMA16(af[m], bfr[n], acc[m][n], 0, 0, 0);               \
    }                                                                          \
    __builtin_amdgcn_s_setprio(0);                                             \
  } while (0)

  if constexpr (AF32) {
    GISSUE(aA, 0, 0);    // tile 0 -> aA, B0 -> Bs[0]
    GISSUE(aB, 1, 64);   // tile 1 -> aB, B1 -> Bs[1]
    asm volatile("s_waitcnt vmcnt(10)" ::: "memory");  // tile 0 (A+B) landed
    AWRITE(aA, 0);
    asm volatile("s_waitcnt lgkmcnt(0)" ::: "memory");
    __builtin_amdgcn_s_barrier();
    __builtin_amdgcn_sched_barrier(0);

    for (int t = 0; t < NT; t += 2) {
      // ---- even sub-iteration: tile t (set aA just freed by AWRITE of tile t) ----
      {
        if (t + 2 < NT) GISSUE(aA, (t + 2) % 3, (t + 2) * 64);
        __builtin_amdgcn_sched_barrier(0);
        COMPUTE(t % 3);
        if (t + 2 < NT)
          asm volatile("s_waitcnt vmcnt(10)" ::: "memory");  // tile t+1 landed
        else
          asm volatile("s_waitcnt vmcnt(0)" ::: "memory");
        AWRITE(aB, (t + 1) % 3);  // tile t+1 (odd -> aB)
        asm volatile("s_waitcnt lgkmcnt(0)" ::: "memory");
        __builtin_amdgcn_s_barrier();
        __builtin_amdgcn_sched_barrier(0);
      }
      // ---- odd sub-iteration: tile t+1 ----
      {
        const int t1 = t + 1;
        if (t1 + 2 < NT) GISSUE(aB, (t1 + 2) % 3, (t1 + 2) * 64);
        __builtin_amdgcn_sched_barrier(0);
        COMPUTE(t1 % 3);
        if (t1 + 1 < NT) {
          if (t1 + 2 < NT)
            asm volatile("s_waitcnt vmcnt(10)" ::: "memory");
          else
            asm volatile("s_waitcnt vmcnt(0)" ::: "memory");
          AWRITE(aA, (t1 + 1) % 3);  // tile t+2 (even -> aA)
          asm volatile("s_waitcnt lgkmcnt(0)" ::: "memory");
          __builtin_amdgcn_s_barrier();
          __builtin_amdgcn_sched_barrier(0);
        }
      }
    }
  } else {
    GSTAGE_BF(0, 0);
    GSTAGE_BF(1, 64);
    asm volatile("s_waitcnt vmcnt(6)" ::: "memory");  // tile 0 landed
    __builtin_amdgcn_s_barrier();
    __builtin_amdgcn_sched_barrier(0);

    for (int t = 0; t < NT; ++t) {
      const int buf = t % 3;
      if (t + 2 < NT) GSTAGE_BF((t + 2) % 3, (t + 2) * 64);
      __builtin_amdgcn_sched_barrier(0);
      COMPUTE(buf);
      if (t + 1 < NT) {
        if (t + 2 < NT)
          asm volatile("s_waitcnt vmcnt(6)" ::: "memory");  // tile t+1 landed
        else
          asm volatile("s_waitcnt vmcnt(0)" ::: "memory");
        __builtin_amdgcn_s_barrier();
        __builtin_amdgcn_sched_barrier(0);
      }
    }
  }
#undef BGLDS
#undef GSTAGE_BF
#undef GISSUE
#undef AWRITE
#undef COMPUTE

#pragma unroll
  for (int n = 0; n < 4; ++n) {
    const int col = col0 + wc * 64 + n * 16 + l15;
    const float bv = bias[col];
#pragma unroll
    for (int m = 0; m < 4; ++m) {
#pragma unroll
      for (int r = 0; r < 4; ++r) {
        const int row = row0 + wr * 64 + m * 16 + lg * 4 + r;
        const float v = (acc[m][n][r] + bv) * oscale;
        if constexpr (OM == 0) {
          ((u16*)Cout)[(size_t)row * N + col] = f2bf(v);
        } else if constexpr (OM == 1) {
          ((float*)Cout)[(size_t)row * N + col] = v;
        } else {
          const int b_ = row >> 11, s_ = row & 2047, h_ = col >> 6, d_ = col & 63;
          ((u16*)Cout)[(size_t)((b_ * 16 + h_) * 64 + d_) * 2048 + s_] = f2bf(v);
        }
      }
    }
  }
}

// -------- flash attention: 32x32x16 MFMA, in-register P via permlane32_swap --------
// (unchanged from round 7, passing at 106 us)
__global__ __launch_bounds__(256, 4) void attn_kernel(
    const u16* __restrict__ Qb, const u16* __restrict__ Kb, const u16* __restrict__ Vt,
    const u32* __restrict__ pm, u16* __restrict__ Oa) {
  __shared__ u16 Ks[2][64 * 64];
  __shared__ u16 Vs[2][64 * 64];
  __shared__ uint4 mlut[16];  // 4 keep-bits -> 4 u32 AND-words
  const int tid = threadIdx.x;
  const int lane = tid & 63;
  const int wid = tid >> 6;
  const int c31 = lane & 31;
  const int hi = lane >> 5;
  const int qt = blockIdx.x;  // 16
  const int hh = blockIdx.y;  // 16
  const int bb = blockIdx.z;  // 4
  const int qbase = qt * 128 + wid * 32;
  const int sw = (lane & 7) << 3;  // LDS read-side XOR swizzle (u16 units)

  if (tid < 16)
    mlut[tid] = make_uint4((u32) - (int)(tid & 1), (u32) - (int)((tid >> 1) & 1),
                           (u32) - (int)((tid >> 2) & 1), (u32) - (int)((tid >> 3) & 1));

  // Q B-fragments: col = q = qbase + c31, k = hi*8 + e, d = ds*16 + k
  const size_t qrow = (size_t)(bb * 2048 + qbase + c31);
  bf16x8 qf[4];
#pragma unroll
  for (int ds = 0; ds < 4; ++ds)
    qf[ds] = *(const bf16x8*)(Qb + qrow * 1024 + hh * 64 + ds * 16 + hi * 8);

  float lrun = 0.f;
  f32x16 oacc[2];
#pragma unroll
  for (int dn = 0; dn < 2; ++dn)
#pragma unroll
    for (int r = 0; r < 16; ++r) oacc[dn][r] = 0.f;

  const size_t kgbase = (size_t)(bb * 2048) * 1024 + hh * 64;
  const size_t vgbase = (size_t)((bb * 16 + hh) * 64) * 2048;

#define STAGE(buf, kbase)                                                              \
  do {                                                                                 \
    _Pragma("unroll") for (int i = 0; i < 2; ++i) {                                    \
      int r = ((i * 256 + tid) * 8) >> 6, c = ((i * 256 + tid) * 8) & 63;              \
      int cs = c ^ ((r & 7) << 3);                                                     \
      glds16(Kb + kgbase + (size_t)((kbase) + r) * 1024 + cs,                          \
             &Ks[buf][(i * 256 + wid * 64) * 8]);                                      \
      glds16(Vt + vgbase + (size_t)r * 2048 + (kbase) + cs,                            \
             &Vs[buf][(i * 256 + wid * 64) * 8]);                                      \
    }                                                                                  \
  } while (0)

  STAGE(0, 0);
  __syncthreads();  // buf0 staged (vmcnt0), mlut visible

  int cur = 0;
  for (int kt = 0; kt < 32; ++kt) {
    if (kt < 31) STAGE(cur ^ 1, (kt + 1) * 64);

    // both 32-key mask words for this tile (row = this lane's q)
    const u64 mw = *(const u64*)(pm + qrow * 64 + kt * 2);
    float ps = 0.f;

#pragma unroll
    for (int kb = 0; kb < 2; ++kb) {
      // QK^T: St[key = kb*32 + (r&3)+8*(r>>2)+4*hi][q = c31]
      f32x16 sacc;
#pragma unroll
      for (int r = 0; r < 16; ++r) sacc[r] = 0.f;
#pragma unroll
      for (int ds = 0; ds < 4; ++ds) {
        bf16x8 kf = *(const bf16x8*)(&Ks[cur][(kb * 32 + c31) * 64 + ((ds * 16 + hi * 8) ^ sw)]);
        sacc = MFMA32(kf, qf[ds], sacc, 0, 0, 0);
      }

      // exp + LUT mask + pack to bf16 pairs (in registers)
      const u32 mwk = (u32)(mw >> (kb * 32));
      u32 Ap[4], Bp[4];
#pragma unroll
      for (int q2 = 0; q2 < 4; ++q2) {
        const u32 kb4 = (mwk >> (q2 * 8 + hi * 4)) & 0xFu;
        const uint4 mm = mlut[kb4];
        const float p0 = __builtin_amdgcn_exp2f(sacc[4 * q2 + 0]);
        const float p1 = __builtin_amdgcn_exp2f(sacc[4 * q2 + 1]);
        const float p2 = __builtin_amdgcn_exp2f(sacc[4 * q2 + 2]);
        const float p3 = __builtin_amdgcn_exp2f(sacc[4 * q2 + 3]);
        const float f0 = __uint_as_float(__float_as_uint(p0) & mm.x);
        const float f1 = __uint_as_float(__float_as_uint(p1) & mm.y);
        const float f2 = __uint_as_float(__float_as_uint(p2) & mm.z);
        const float f3 = __uint_as_float(__float_as_uint(p3) & mm.w);
        ps += (f0 + f1) + (f2 + f3);
        Ap[q2] = cvtpk(f0, f1);
        Bp[q2] = cvtpk(f2, f3);
      }

      // redistribute across hi-halves: B-frag regs r0,r2 from A-pair swap, r1,r3 from B-pair
      asm("v_permlane32_swap_b32 %0, %1" : "+v"(Ap[0]), "+v"(Ap[1]));
      asm("v_permlane32_swap_b32 %0, %1" : "+v"(Bp[0]), "+v"(Bp[1]));
      asm("v_permlane32_swap_b32 %0, %1" : "+v"(Ap[2]), "+v"(Ap[3]));
      asm("v_permlane32_swap_b32 %0, %1" : "+v"(Bp[2]), "+v"(Bp[3]));

      // PV: O^T[d][q] += V^T[d][key] * P[key][q], 2 key-steps of 16 per kb
#pragma unroll
      for (int t = 0; t < 2; ++t) {
        uint4 fr;
        fr.x = Ap[2 * t]; fr.y = Bp[2 * t]; fr.z = Ap[2 * t + 1]; fr.w = Bp[2 * t + 1];
        const bf16x8 pf = *(const bf16x8*)&fr;
        const int koff = (kb * 2 + t) * 16 + hi * 8;
#pragma unroll
        for (int dn = 0; dn < 2; ++dn) {
          bf16x8 vf = *(const bf16x8*)(&Vs[cur][(dn * 32 + c31) * 64 + (koff ^ sw)]);
          oacc[dn] = MFMA32(vf, pf, oacc[dn], 0, 0, 0);
        }
      }
    }

    ps += __shfl_xor(ps, 32);
    lrun += ps;

    __syncthreads();  // vmcnt(0): next tile staged; lgkmcnt(0): buf[cur] reads done
    cur ^= 1;
  }
#undef STAGE

  // epilogue: O[q][d], lane owns q = qbase + c31; d = dn*32 + q2*8 + hi*4 + {0..3}
  const float inv = 1.0f / lrun;
  u16* orow = Oa + qrow * 1024 + hh * 64;
#pragma unroll
  for (int dn = 0; dn < 2; ++dn) {
#pragma unroll
    for (int q2 = 0; q2 < 4; ++q2) {
      uint2 w;
      w.x = cvtpk(oacc[dn][4 * q2 + 0] * inv, oacc[dn][4 * q2 + 1] * inv);
      w.y = cvtpk(oacc[dn][4 * q2 + 2] * inv, oacc[dn][4 * q2 + 3] * inv);
      *(uint2*)(orow + dn * 32 + q2 * 8 + hi * 4) = w;
    }
  }
}

extern "C" void kernel_launch(void* const* d_in, const int* in_sizes, int n_in,
                              void* d_out, int out_size, void* d_ws, size_t ws_size,
                              hipStream_t stream) {
  const float* q = (const float*)d_in[0];
  const float* k = (const float*)d_in[1];
  const float* v = (const float*)d_in[2];
  const int* mask = (const int*)d_in[3];
  const float* Wq = (const float*)d_in[4]; const float* bq = (const float*)d_in[5];
  const float* Wk = (const float*)d_in[6]; const float* bk = (const float*)d_in[7];
  const float* Wv = (const float*)d_in[8]; const float* bv = (const float*)d_in[9];
  const float* Wo = (const float*)d_in[10]; const float* bo = (const float*)d_in[11];
  float* out = (float*)d_out;
  char* ws = (char*)d_ws;
  const size_t MB = 1024ull * 1024ull;
  u16* Oa  = (u16*)(ws + 0 * MB);    // 16 MB (attention output, bf16)
  u16* Qp  = (u16*)(ws + 48 * MB);   // 16 MB each
  u16* Kp  = (u16*)(ws + 64 * MB);
  u16* Vtp = (u16*)(ws + 80 * MB);
  u16* Wqt = (u16*)(ws + 96 * MB);   // 2 MB each
  u16* Wkt = (u16*)(ws + 98 * MB);
  u16* Wvt = (u16*)(ws + 100 * MB);
  u16* Wot = (u16*)(ws + 102 * MB);
  u32* pmb = (u32*)(ws + 104 * MB);  // 2 MB

  const float QSCALE = 0.125f * L2E;  // fold score scale + log2(e) into Q projection

  wtrans_kernel<<<dim3(16, 16, 4), 256, 0, stream>>>(Wq, Wk, Wv, Wo, Wqt, Wkt, Wvt, Wot);
  packmask_kernel<<<dim3(65536), 256, 0, stream>>>(mask, pmb);
  gemm_kernel<0><<<dim3(32, 8), 512, 0, stream>>>(q, Wqt, bq, Qp, QSCALE);
  gemm_kernel<0><<<dim3(32, 8), 512, 0, stream>>>(k, Wkt, bk, Kp, 1.0f);
  gemm_kernel<2><<<dim3(32, 8), 512, 0, stream>>>(v, Wvt, bv, Vtp, 1.0f);
  attn_kernel<<<dim3(16, 16, 4), 256, 0, stream>>>(Qp, Kp, Vtp, pmb, Oa);
  gemm_kernel<1><<<dim3(32, 8), 512, 0, stream>>>(Oa, Wot, bo, out, 1.0f);
}